// Round 22
// baseline (216.475 us; speedup 1.0000x reference)
//
#include <hip/hip_runtime.h>

#define NROWS 65536
#define KC    1024
#define DIM   128
#define W_DIST 3.5e-5f   // validated R18/R19

typedef short  bf16x8 __attribute__((ext_vector_type(8)));
typedef float  f32x4  __attribute__((ext_vector_type(4)));
typedef float  f32x16 __attribute__((ext_vector_type(16)));

#define ZERO16 ((f32x16){0.f,0.f,0.f,0.f,0.f,0.f,0.f,0.f,0.f,0.f,0.f,0.f,0.f,0.f,0.f,0.f})

__device__ __forceinline__ unsigned short f2bf_rne(float f) {
    unsigned int u = __float_as_uint(f);
    u += 0x7FFFu + ((u >> 16) & 1u);
    return (unsigned short)(u >> 16);
}
__device__ __forceinline__ float bf2f(unsigned short h) {
    return __uint_as_float(((unsigned int)h) << 16);
}

// async global->LDS DMA, 16 B per lane; LDS dest = wave-uniform base + lane*16
__device__ __forceinline__ void gll16(const unsigned short* g, short* l) {
    __builtin_amdgcn_global_load_lds(
        (const __attribute__((address_space(1))) unsigned int*)g,
        (__attribute__((address_space(3))) unsigned int*)l,
        16, 0, 0);
}

template <int N>
__device__ __forceinline__ void vmwait() {
    if constexpr (N == 4)      asm volatile("s_waitcnt vmcnt(4)" ::: "memory");
    else if constexpr (N == 2) asm volatile("s_waitcnt vmcnt(2)" ::: "memory");
    else if constexpr (N == 1) asm volatile("s_waitcnt vmcnt(1)" ::: "memory");
    else                       asm volatile("s_waitcnt vmcnt(0)" ::: "memory");
}

// numpy pairwise sum-of-squares for n=128 (8 stride-8 accumulators, tree combine)
__device__ __forceinline__ float np_sumsq_128(const float* v) {
    float r[8];
    #pragma unroll
    for (int j = 0; j < 8; ++j) r[j] = __fmul_rn(v[j], v[j]);
    #pragma unroll
    for (int i = 1; i < 16; ++i)
        #pragma unroll
        for (int j = 0; j < 8; ++j)
            r[j] = __fadd_rn(r[j], __fmul_rn(v[i * 8 + j], v[i * 8 + j]));
    return __fadd_rn(__fadd_rn(__fadd_rn(r[0], r[1]), __fadd_rn(r[2], r[3])),
                     __fadd_rn(__fadd_rn(r[4], r[5]), __fadd_rn(r[6], r[7])));
}

// ---- codebook prep: 8 threads per row; bit-exact numpy-pairwise norm ------
__global__ __launch_bounds__(256) void vq_prep(const float* __restrict__ emb,
        float* __restrict__ enorm,
        unsigned short* __restrict__ eh, unsigned short* __restrict__ em) {
    const int t = blockIdx.x * 256 + threadIdx.x;   // 8192 threads
    const int k = t >> 3;
    const int j = t & 7;
    const float* row = emb + (size_t)k * DIM;

    float r = __fmul_rn(row[j], row[j]);
    #pragma unroll
    for (int i = 1; i < 16; ++i) {
        float v = row[i * 8 + j];
        r = __fadd_rn(r, __fmul_rn(v, v));
    }
    r = __fadd_rn(r, __shfl_xor(r, 1, 64));
    r = __fadd_rn(r, __shfl_xor(r, 2, 64));
    r = __fadd_rn(r, __shfl_xor(r, 4, 64));
    if (j == 0) enorm[k] = r;

    const float4* p = reinterpret_cast<const float4*>(row + j * 16);
    unsigned int h[16], m[16];
    #pragma unroll
    for (int q = 0; q < 4; ++q) {
        float4 v4 = p[q];
        float f[4] = {v4.x, v4.y, v4.z, v4.w};
        #pragma unroll
        for (int c = 0; c < 4; ++c) {
            unsigned short hh = f2bf_rne(f[c]);
            h[q * 4 + c] = hh;
            m[q * 4 + c] = f2bf_rne(f[c] - bf2f(hh));
        }
    }
    uint4 vh0 = {h[0] | (h[1] << 16), h[2] | (h[3] << 16),
                 h[4] | (h[5] << 16), h[6] | (h[7] << 16)};
    uint4 vh1 = {h[8] | (h[9] << 16), h[10] | (h[11] << 16),
                 h[12] | (h[13] << 16), h[14] | (h[15] << 16)};
    uint4 vm0 = {m[0] | (m[1] << 16), m[2] | (m[3] << 16),
                 m[4] | (m[5] << 16), m[6] | (m[7] << 16)};
    uint4 vm1 = {m[8] | (m[9] << 16), m[10] | (m[11] << 16),
                 m[12] | (m[13] << 16), m[14] | (m[15] << 16)};
    unsigned short* ph = eh + (size_t)k * DIM + j * 16;
    unsigned short* pm = em + (size_t)k * DIM + j * 16;
    *reinterpret_cast<uint4*>(ph) = vh0;
    *reinterpret_cast<uint4*>(ph + 8) = vh1;
    *reinterpret_cast<uint4*>(pm) = vm0;
    *reinterpret_cast<uint4*>(pm + 8) = vm1;
}

// ---- main MFMA distance + top-2 kernel + loss partial ---------------------
// R13 schedule, but 512-thread blocks (8 waves, 256 rows): 2 blocks/CU =
// 16 waves/CU = 4 waves/SIMD (vs 2) -- doubles the latency-hiding pool over
// the same barrier structure, and 8 waves share each staged E tile (per-CU
// E L2-traffic halves). VGPR cap at 4 waves/EU = 128 >= measured 116.
// Each wave stages 64 units/part -> 1 gll16 per part; vmcnt counted at 2.
__global__ __launch_bounds__(512, 4) void vq_mfma(
        const float* __restrict__ x,
        const unsigned short* __restrict__ eh, const unsigned short* __restrict__ em,
        const float* __restrict__ enorm,
        int* __restrict__ bestk, float* __restrict__ idx_out,
        int* __restrict__ fb_cnt, int* __restrict__ fb_rows,
        double* __restrict__ partials) {
    const int tid  = threadIdx.x;
    const int lane = tid & 63;
    const int wid  = tid >> 6;                 // 0..7
    const int lr31 = lane & 31;
    const int hi   = lane >> 5;
    const int rtile = blockIdx.x * 256 + wid * 32;

    __shared__ short ldsE[3][2][4096];   // 3 bufs x (hi,mid) x 8 KB = 48 KB
    __shared__ float s_enorm[KC];        // 4 KB
    __shared__ double sloss[8];

    // staging decode: unit u (16 B) = [s2 = u>>5][row = u&31]; wave w owns
    // units [w*64, w*64+64) of EACH part via 1 gll16 per part.
    const int su  = wid * 64 + lane;
    const int src = (su & 31) * DIM + (su >> 5) * 8;
    const int dst = su * 8;                    // in shorts

#define VQ_STAGE(T, B)                                                      \
    do {                                                                    \
        gll16(eh + (size_t)(T) * 4096 + src, &ldsE[B][0][dst]);             \
        gll16(em + (size_t)(T) * 4096 + src, &ldsE[B][1][dst]);             \
    } while (0)

    // X fragments: lane owns row rtile+lr31, k = s*16 + hi*8 .. +8 (s=0..7);
    // accumulate this lane's half-row sum-of-squares for the loss.
    bf16x8 fxh[8], fxm[8];
    float xn;
    {
        const float* px = x + (size_t)(rtile + lr31) * DIM + hi * 8;
        float c0 = 0.f, c1 = 0.f, c2 = 0.f, c3 = 0.f;
        #pragma unroll
        for (int s = 0; s < 8; ++s) {
            float4 a = *reinterpret_cast<const float4*>(px + s * 16);
            float4 b = *reinterpret_cast<const float4*>(px + s * 16 + 4);
            c0 = fmaf(a.x, a.x, c0); c1 = fmaf(a.y, a.y, c1);
            c2 = fmaf(a.z, a.z, c2); c3 = fmaf(a.w, a.w, c3);
            c0 = fmaf(b.x, b.x, c0); c1 = fmaf(b.y, b.y, c1);
            c2 = fmaf(b.z, b.z, c2); c3 = fmaf(b.w, b.w, c3);
            float f[8] = {a.x, a.y, a.z, a.w, b.x, b.y, b.z, b.w};
            bf16x8 vh, vm;
            #pragma unroll
            for (int j = 0; j < 8; ++j) {
                unsigned short hh = f2bf_rne(f[j]);
                vh[j] = (short)hh;
                vm[j] = (short)f2bf_rne(f[j] - bf2f(hh));
            }
            fxh[s] = vh; fxm[s] = vm;
        }
        xn = (c0 + c1) + (c2 + c3);
        xn += __shfl_xor(xn, 32, 64);   // merge the two half-rows -> full ||x||^2
    }
    #pragma unroll
    for (int s = 0; s < 8; ++s)
        asm volatile("" : "+v"(fxh[s]), "+v"(fxm[s]));

    // enorm -> LDS (4 KB, 512 threads x 2 floats)
    *reinterpret_cast<float2*>(&s_enorm[tid * 2]) =
        *reinterpret_cast<const float2*>(&enorm[tid * 2]);

    VQ_STAGE(0, 0);
    VQ_STAGE(1, 1);

    // commit own ds_writes, sync; do NOT drain the staging DMA
    asm volatile("s_waitcnt lgkmcnt(0)" ::: "memory");
    __builtin_amdgcn_s_barrier();

    float m1 = 1e30f, m2 = 1e30f; int k1 = 0;
    f32x16 aE, dE, aO, dO;

#define VQ_EPI(T, PA, PD)                                                   \
    do {                                                                    \
        const int _kb = (T) * 32 + (hi << 2);                               \
        _Pragma("unroll")                                                   \
        for (int g = 0; g < 4; ++g) {                                       \
            const f32x4 _nr = *reinterpret_cast<const f32x4*>(&s_enorm[_kb + g * 8]); \
            _Pragma("unroll")                                               \
            for (int j = 0; j < 4; ++j) {                                   \
                const int _r = g * 4 + j;                                   \
                float _v = fmaf(-2.0f, PA[_r] + PD[_r], _nr[j]);            \
                int _kk = _kb + g * 8 + j;                                  \
                bool _lt = _v < m1;                                         \
                m2 = fminf(m2, fmaxf(m1, _v));                              \
                k1 = _lt ? _kk : k1;                                        \
                m1 = fminf(m1, _v);                                         \
            }                                                               \
        }                                                                   \
    } while (0)

#define VQ_ITER(T, B, SB, CA, CD, PA, PD, VMN, DOSTAGE, DOEPI)              \
    do {                                                                    \
        vmwait<VMN>();                                                      \
        __builtin_amdgcn_s_barrier();                                       \
        asm volatile("" ::: "memory");                                      \
        CA = ZERO16; CD = ZERO16;                                           \
        __builtin_amdgcn_s_setprio(1);                                      \
        _Pragma("unroll")                                                   \
        for (int s = 0; s < 8; ++s) {                                       \
            const int _u = ((s * 2 + hi) * 32 + lr31) * 8;                  \
            bf16x8 feh = *reinterpret_cast<const bf16x8*>(&ldsE[B][0][_u]); \
            bf16x8 fem = *reinterpret_cast<const bf16x8*>(&ldsE[B][1][_u]); \
            CA = __builtin_amdgcn_mfma_f32_32x32x16_bf16(feh, fxh[s], CA, 0, 0, 0); \
            CD = __builtin_amdgcn_mfma_f32_32x32x16_bf16(feh, fxm[s], CD, 0, 0, 0); \
            CD = __builtin_amdgcn_mfma_f32_32x32x16_bf16(fem, fxh[s], CD, 0, 0, 0); \
        }                                                                   \
        __builtin_amdgcn_s_setprio(0);                                      \
        if (DOSTAGE) { VQ_STAGE((T) + 2, SB); }                             \
        if (DOEPI)   { VQ_EPI((T) - 1, PA, PD); }                           \
    } while (0)

    VQ_ITER(0, 0, 2, aE, dE, aO, dO, 2, 1, 0);
    VQ_ITER(1, 1, 0, aO, dO, aE, dE, 2, 1, 1);
    VQ_ITER(2, 2, 1, aE, dE, aO, dO, 2, 1, 1);
    VQ_ITER(3, 0, 2, aO, dO, aE, dE, 2, 1, 1);
    VQ_ITER(4, 1, 0, aE, dE, aO, dO, 2, 1, 1);
    VQ_ITER(5, 2, 1, aO, dO, aE, dE, 2, 1, 1);
    for (int tb = 6; tb < 30; tb += 6) {
        VQ_ITER(tb + 0, 0, 2, aE, dE, aO, dO, 2, 1, 1);
        VQ_ITER(tb + 1, 1, 0, aO, dO, aE, dE, 2, 1, 1);
        VQ_ITER(tb + 2, 2, 1, aE, dE, aO, dO, 2, 1, 1);
        VQ_ITER(tb + 3, 0, 2, aO, dO, aE, dE, 2, 1, 1);
        VQ_ITER(tb + 4, 1, 0, aE, dE, aO, dO, 2, 1, 1);
        VQ_ITER(tb + 5, 2, 1, aO, dO, aE, dE, 2, 1, 1);
    }
    VQ_ITER(30, 0, 2, aE, dE, aO, dO, 2, 0, 1);
    VQ_ITER(31, 1, 0, aO, dO, aE, dE, 0, 0, 1);
    VQ_EPI(31, aO, dO);
#undef VQ_ITER
#undef VQ_EPI
#undef VQ_STAGE

    // merge the two k-subsets per x-row (lane L and L+32 share row lane&31)
    {
        float om1 = __shfl_xor(m1, 32, 64);
        float om2 = __shfl_xor(m2, 32, 64);
        int   ok1 = __shfl_xor(k1, 32, 64);
        float mx = fmaxf(m1, om1);
        m2 = fminf(fminf(m2, om2), mx);
        bool take = (om1 < m1) || (om1 == m1 && ok1 < k1);
        k1 = take ? ok1 : k1;
        m1 = fminf(m1, om1);
    }

    // loss partial: min distance = m1 + ||x||^2; both duplicated across the
    // lane/lane+32 pair -> 64-lane butterfly sum = 2x row sum -> x0.5.
    {
        float ls = m1 + xn;
        #pragma unroll
        for (int off = 1; off < 64; off <<= 1) ls += __shfl_xor(ls, off, 64);
        if (lane == 0) sloss[wid] = (double)ls * 0.5;
    }
    __syncthreads();
    if (tid == 0) {
        double s = ((sloss[0] + sloss[1]) + (sloss[2] + sloss[3]))
                 + ((sloss[4] + sloss[5]) + (sloss[6] + sloss[7]));
        partials[blockIdx.x] = s;
    }

    if (lane < 32) {
        const int row = rtile + lane;
        if (m2 - m1 < W_DIST) {          // ambiguous under rounding: refine
            int slot = atomicAdd(fb_cnt, 1);
            fb_rows[slot] = row;
        } else {
            bestk[row] = k1;
            idx_out[row] = (float)k1;
        }
    }
}

// ---- exact fallback: block-cooperative, 8 rows per codebook pass ----------
__global__ __launch_bounds__(512) void vq_fallback(
        const float* __restrict__ x, const float* __restrict__ emb,
        const float* __restrict__ enorm,
        const int* __restrict__ fb_cnt, const int* __restrict__ fb_rows,
        int* __restrict__ bestk, float* __restrict__ idx_out) {
    const int tid  = threadIdx.x;
    const int lane = tid & 63;
    const int wid  = tid >> 6;          // 8 waves
    const int nb = *fb_cnt;

    __shared__ float sx[8][DIM];        // 4 KB staged x rows
    __shared__ float s_xn[8];
    __shared__ float swv[8][8];         // [wave][row] candidates
    __shared__ int   swk[8][8];

    const float en0 = enorm[tid];       // k0 = tid
    const float en1 = enorm[tid + 512]; // k1 = tid + 512
    const float4* e0p = reinterpret_cast<const float4*>(emb + (size_t)tid * DIM);
    const float4* e1p = reinterpret_cast<const float4*>(emb + (size_t)(tid + 512) * DIM);

    for (int base = blockIdx.x * 8; base < nb; base += gridDim.x * 8) {
        const int R = min(8, nb - base);
        {
            const int r = tid >> 6;
            const int c2 = (tid & 63) * 2;
            const int slot = fb_rows[min(base + r, nb - 1)];
            float2 v = *reinterpret_cast<const float2*>(x + (size_t)slot * DIM + c2);
            sx[r][c2] = v.x; sx[r][c2 + 1] = v.y;
        }
        __syncthreads();
        if (tid < 8) s_xn[tid] = np_sumsq_128(&sx[tid][0]);
        __syncthreads();

        float a0[8][4], a1[8][4];
        #pragma unroll
        for (int r = 0; r < 8; ++r)
            #pragma unroll
            for (int c = 0; c < 4; ++c) { a0[r][c] = 0.f; a1[r][c] = 0.f; }

        for (int q = 0; q < 32; q += 4) {
            float4 e0v[4], e1v[4];
            #pragma unroll
            for (int j = 0; j < 4; ++j) { e0v[j] = e0p[q + j]; e1v[j] = e1p[q + j]; }
            #pragma unroll
            for (int j = 0; j < 4; ++j) {
                #pragma unroll
                for (int r = 0; r < 8; ++r) {
                    float4 xv = *reinterpret_cast<const float4*>(&sx[r][(q + j) * 4]);
                    a0[r][0] = fmaf(xv.x, e0v[j].x, a0[r][0]);
                    a0[r][1] = fmaf(xv.y, e0v[j].y, a0[r][1]);
                    a0[r][2] = fmaf(xv.z, e0v[j].z, a0[r][2]);
                    a0[r][3] = fmaf(xv.w, e0v[j].w, a0[r][3]);
                    a1[r][0] = fmaf(xv.x, e1v[j].x, a1[r][0]);
                    a1[r][1] = fmaf(xv.y, e1v[j].y, a1[r][1]);
                    a1[r][2] = fmaf(xv.z, e1v[j].z, a1[r][2]);
                    a1[r][3] = fmaf(xv.w, e1v[j].w, a1[r][3]);
                }
            }
        }

        float cv[8]; int ck[8];
        #pragma unroll
        for (int r = 0; r < 8; ++r) {
            float xn = s_xn[r];
            float d0 = __fadd_rn(__fadd_rn(a0[r][0], a0[r][1]),
                                 __fadd_rn(a0[r][2], a0[r][3]));
            float s0 = __fsub_rn(__fadd_rn(xn, en0), __fmul_rn(2.0f, d0));
            float d1 = __fadd_rn(__fadd_rn(a1[r][0], a1[r][1]),
                                 __fadd_rn(a1[r][2], a1[r][3]));
            float s1 = __fsub_rn(__fadd_rn(xn, en1), __fmul_rn(2.0f, d1));
            bool t1 = (s1 < s0);
            cv[r] = t1 ? s1 : s0;
            ck[r] = t1 ? tid + 512 : tid;
        }
        #pragma unroll
        for (int off = 1; off < 64; off <<= 1) {
            #pragma unroll
            for (int r = 0; r < 8; ++r) {
                float ov = __shfl_xor(cv[r], off, 64);
                int   ok = __shfl_xor(ck[r], off, 64);
                bool take = (ov < cv[r]) || (ov == cv[r] && ok < ck[r]);
                cv[r] = take ? ov : cv[r];
                ck[r] = take ? ok : ck[r];
            }
        }
        if (lane == 0) {
            #pragma unroll
            for (int r = 0; r < 8; ++r) { swv[wid][r] = cv[r]; swk[wid][r] = ck[r]; }
        }
        __syncthreads();
        if (tid < R) {
            float bv = swv[0][tid]; int bk = swk[0][tid];
            #pragma unroll
            for (int w = 1; w < 8; ++w) {
                float v = swv[w][tid]; int k = swk[w][tid];
                bool take = (v < bv) || (v == bv && k < bk);
                bv = take ? v : bv;
                bk = take ? k : bk;
            }
            const int row = fb_rows[base + tid];
            bestk[row] = bk;
            idx_out[row] = (float)bk;
        }
        __syncthreads();
    }
}

// ---- gather quantized rows (no x read, no loss math) ----------------------
__global__ __launch_bounds__(256) void vq_gather(
        const float* __restrict__ emb, const int* __restrict__ bestk,
        float* __restrict__ quant) {
    const int t = blockIdx.x * 256 + threadIdx.x;   // 1048576 threads, 8 elems
    const int r = t >> 4;
    const int c = (t & 15) * 8;
    const int bk = bestk[r];
    const float4* ep = reinterpret_cast<const float4*>(emb + (size_t)bk * DIM + c);
    float4 e0 = ep[0], e1 = ep[1];
    float* q = quant + (size_t)r * DIM + c;   // base misaligned by 1 float
    q[0] = e0.x; q[1] = e0.y; q[2] = e0.z; q[3] = e0.w;
    q[4] = e1.x; q[5] = e1.y; q[6] = e1.z; q[7] = e1.w;
}

// ---- final loss: sum 256 block partials in one block ----------------------
__global__ __launch_bounds__(256) void vq_loss(
        const double* __restrict__ partials, float* __restrict__ out) {
    double s = partials[threadIdx.x];
    #pragma unroll
    for (int off = 32; off > 0; off >>= 1) s += __shfl_down(s, off, 64);
    __shared__ double sd[4];
    if ((threadIdx.x & 63) == 0) sd[threadIdx.x >> 6] = s;
    __syncthreads();
    if (threadIdx.x == 0)
        out[0] = (float)(((sd[0] + sd[1]) + (sd[2] + sd[3])) * (1.25 / 8388608.0));
}

extern "C" void kernel_launch(void* const* d_in, const int* in_sizes, int n_in,
                              void* d_out, int out_size, void* d_ws, size_t ws_size,
                              hipStream_t stream) {
    const float* x   = (const float*)d_in[0];   // [32,2048,128] f32
    const float* emb = (const float*)d_in[1];   // [1024,128] f32

    float* out      = (float*)d_out;
    float* loss_out = out;
    float* quant    = out + 1;                        // [8388608]
    float* idx_out  = out + 1 + (size_t)NROWS * DIM;  // [65536] as float

    char* ws = (char*)d_ws;
    int*    fb_cnt   = (int*)(ws + 8);
    float*  enorm    = (float*)(ws + 1024);             // 4 KB
    int*    fb_rows  = (int*)(ws + 16384);              // 256 KB
    int*    bestk    = (int*)(ws + 278528);             // 256 KB
    unsigned short* eh = (unsigned short*)(ws + 557056); // 256 KB
    unsigned short* em = (unsigned short*)(ws + 819200); // 256 KB
    double* partials = (double*)(ws + 1081344);          // 2 KB (256 doubles)

    hipMemsetAsync(ws, 0, 16, stream);
    vq_prep<<<32, 256, 0, stream>>>(emb, enorm, eh, em);
    vq_mfma<<<256, 512, 0, stream>>>(x, eh, em, enorm,
                                     bestk, idx_out, fb_cnt, fb_rows, partials);
    vq_fallback<<<1024, 512, 0, stream>>>(x, emb, enorm, fb_cnt, fb_rows,
                                          bestk, idx_out);
    vq_gather<<<4096, 256, 0, stream>>>(emb, bestk, quant);
    vq_loss<<<1, 256, 0, stream>>>(partials, loss_out);
}

// Round 23
// 96.544 us; speedup vs baseline: 2.2422x; 2.2422x over previous
//
#include <hip/hip_runtime.h>

#define NROWS 65536
#define KC    1024
#define DIM   128
#define W_DIST 3.5e-5f   // validated R18/R19

typedef short  bf16x8 __attribute__((ext_vector_type(8)));
typedef float  f32x4  __attribute__((ext_vector_type(4)));
typedef float  f32x16 __attribute__((ext_vector_type(16)));

#define ZERO16 ((f32x16){0.f,0.f,0.f,0.f,0.f,0.f,0.f,0.f,0.f,0.f,0.f,0.f,0.f,0.f,0.f,0.f})

__device__ __forceinline__ unsigned short f2bf_rne(float f) {
    unsigned int u = __float_as_uint(f);
    u += 0x7FFFu + ((u >> 16) & 1u);
    return (unsigned short)(u >> 16);
}
__device__ __forceinline__ float bf2f(unsigned short h) {
    return __uint_as_float(((unsigned int)h) << 16);
}

// async global->LDS DMA, 16 B per lane; LDS dest = wave-uniform base + lane*16
__device__ __forceinline__ void gll16(const unsigned short* g, short* l) {
    __builtin_amdgcn_global_load_lds(
        (const __attribute__((address_space(1))) unsigned int*)g,
        (__attribute__((address_space(3))) unsigned int*)l,
        16, 0, 0);
}

template <int N>
__device__ __forceinline__ void vmwait() {
    if constexpr (N == 8)      asm volatile("s_waitcnt vmcnt(8)" ::: "memory");
    else if constexpr (N == 4) asm volatile("s_waitcnt vmcnt(4)" ::: "memory");
    else if constexpr (N == 2) asm volatile("s_waitcnt vmcnt(2)" ::: "memory");
    else                       asm volatile("s_waitcnt vmcnt(0)" ::: "memory");
}

// numpy pairwise sum-of-squares for n=128 (8 stride-8 accumulators, tree combine)
__device__ __forceinline__ float np_sumsq_128(const float* v) {
    float r[8];
    #pragma unroll
    for (int j = 0; j < 8; ++j) r[j] = __fmul_rn(v[j], v[j]);
    #pragma unroll
    for (int i = 1; i < 16; ++i)
        #pragma unroll
        for (int j = 0; j < 8; ++j)
            r[j] = __fadd_rn(r[j], __fmul_rn(v[i * 8 + j], v[i * 8 + j]));
    return __fadd_rn(__fadd_rn(__fadd_rn(r[0], r[1]), __fadd_rn(r[2], r[3])),
                     __fadd_rn(__fadd_rn(r[4], r[5]), __fadd_rn(r[6], r[7])));
}

// ---- codebook prep: 8 threads per row; bit-exact numpy-pairwise norm ------
__global__ __launch_bounds__(256) void vq_prep(const float* __restrict__ emb,
        float* __restrict__ enorm,
        unsigned short* __restrict__ eh, unsigned short* __restrict__ em) {
    const int t = blockIdx.x * 256 + threadIdx.x;   // 8192 threads
    const int k = t >> 3;
    const int j = t & 7;
    const float* row = emb + (size_t)k * DIM;

    float r = __fmul_rn(row[j], row[j]);
    #pragma unroll
    for (int i = 1; i < 16; ++i) {
        float v = row[i * 8 + j];
        r = __fadd_rn(r, __fmul_rn(v, v));
    }
    r = __fadd_rn(r, __shfl_xor(r, 1, 64));
    r = __fadd_rn(r, __shfl_xor(r, 2, 64));
    r = __fadd_rn(r, __shfl_xor(r, 4, 64));
    if (j == 0) enorm[k] = r;

    const float4* p = reinterpret_cast<const float4*>(row + j * 16);
    unsigned int h[16], m[16];
    #pragma unroll
    for (int q = 0; q < 4; ++q) {
        float4 v4 = p[q];
        float f[4] = {v4.x, v4.y, v4.z, v4.w};
        #pragma unroll
        for (int c = 0; c < 4; ++c) {
            unsigned short hh = f2bf_rne(f[c]);
            h[q * 4 + c] = hh;
            m[q * 4 + c] = f2bf_rne(f[c] - bf2f(hh));
        }
    }
    uint4 vh0 = {h[0] | (h[1] << 16), h[2] | (h[3] << 16),
                 h[4] | (h[5] << 16), h[6] | (h[7] << 16)};
    uint4 vh1 = {h[8] | (h[9] << 16), h[10] | (h[11] << 16),
                 h[12] | (h[13] << 16), h[14] | (h[15] << 16)};
    uint4 vm0 = {m[0] | (m[1] << 16), m[2] | (m[3] << 16),
                 m[4] | (m[5] << 16), m[6] | (m[7] << 16)};
    uint4 vm1 = {m[8] | (m[9] << 16), m[10] | (m[11] << 16),
                 m[12] | (m[13] << 16), m[14] | (m[15] << 16)};
    unsigned short* ph = eh + (size_t)k * DIM + j * 16;
    unsigned short* pm = em + (size_t)k * DIM + j * 16;
    *reinterpret_cast<uint4*>(ph) = vh0;
    *reinterpret_cast<uint4*>(ph + 8) = vh1;
    *reinterpret_cast<uint4*>(pm) = vm0;
    *reinterpret_cast<uint4*>(pm + 8) = vm1;
}

// ---- main MFMA distance + top-2 kernel + loss partial ---------------------
// R13 (=R9) structure; loss partial = sum of (m1 + ||x_row||^2).
// Plateau note: R11/R12/R14/R15/R16/R22 restructures all regressed.
// (R22: __launch_bounds__(512,4) forced VGPR 64 -> catastrophic spill.)
__global__ __launch_bounds__(256, 2) void vq_mfma(
        const float* __restrict__ x,
        const unsigned short* __restrict__ eh, const unsigned short* __restrict__ em,
        const float* __restrict__ enorm,
        int* __restrict__ bestk, float* __restrict__ idx_out,
        int* __restrict__ fb_cnt, int* __restrict__ fb_rows,
        double* __restrict__ partials) {
    const int tid  = threadIdx.x;
    const int lane = tid & 63;
    const int wid  = tid >> 6;
    const int lr31 = lane & 31;
    const int hi   = lane >> 5;
    const int rtile = blockIdx.x * 128 + wid * 32;

    __shared__ short ldsE[3][2][4096];   // 3 bufs x (hi,mid) x 8 KB = 48 KB
    __shared__ float s_enorm[KC];        // 4 KB
    __shared__ double sloss[4];

    const int u0 = wid * 128 + lane;
    const int u1 = wid * 128 + 64 + lane;
    const int src0 = (u0 & 31) * DIM + (u0 >> 5) * 8;
    const int src1 = (u1 & 31) * DIM + (u1 >> 5) * 8;
    const int dst0 = wid * 128 * 8;          // in shorts
    const int dst1 = (wid * 128 + 64) * 8;

#define VQ_STAGE(T, B)                                                      \
    do {                                                                    \
        const unsigned short* _gh = eh + (size_t)(T) * 4096;                \
        const unsigned short* _gm = em + (size_t)(T) * 4096;                \
        gll16(_gh + src0, &ldsE[B][0][dst0]);                               \
        gll16(_gh + src1, &ldsE[B][0][dst1]);                               \
        gll16(_gm + src0, &ldsE[B][1][dst0]);                               \
        gll16(_gm + src1, &ldsE[B][1][dst1]);                               \
    } while (0)

    // X fragments: lane owns row rtile+lr31, k = s*16 + hi*8 .. +8 (s=0..7);
    // accumulate this lane's half-row sum-of-squares for the loss.
    bf16x8 fxh[8], fxm[8];
    float xn;
    {
        const float* px = x + (size_t)(rtile + lr31) * DIM + hi * 8;
        float c0 = 0.f, c1 = 0.f, c2 = 0.f, c3 = 0.f;
        #pragma unroll
        for (int s = 0; s < 8; ++s) {
            float4 a = *reinterpret_cast<const float4*>(px + s * 16);
            float4 b = *reinterpret_cast<const float4*>(px + s * 16 + 4);
            c0 = fmaf(a.x, a.x, c0); c1 = fmaf(a.y, a.y, c1);
            c2 = fmaf(a.z, a.z, c2); c3 = fmaf(a.w, a.w, c3);
            c0 = fmaf(b.x, b.x, c0); c1 = fmaf(b.y, b.y, c1);
            c2 = fmaf(b.z, b.z, c2); c3 = fmaf(b.w, b.w, c3);
            float f[8] = {a.x, a.y, a.z, a.w, b.x, b.y, b.z, b.w};
            bf16x8 vh, vm;
            #pragma unroll
            for (int j = 0; j < 8; ++j) {
                unsigned short hh = f2bf_rne(f[j]);
                vh[j] = (short)hh;
                vm[j] = (short)f2bf_rne(f[j] - bf2f(hh));
            }
            fxh[s] = vh; fxm[s] = vm;
        }
        xn = (c0 + c1) + (c2 + c3);
        xn += __shfl_xor(xn, 32, 64);   // merge the two half-rows -> full ||x||^2
    }
    #pragma unroll
    for (int s = 0; s < 8; ++s)
        asm volatile("" : "+v"(fxh[s]), "+v"(fxm[s]));

    // enorm -> LDS (4 KB)
    *reinterpret_cast<float4*>(&s_enorm[tid * 4]) =
        *reinterpret_cast<const float4*>(&enorm[tid * 4]);

    VQ_STAGE(0, 0);
    VQ_STAGE(1, 1);

    // commit own ds_writes, sync; do NOT drain the staging DMA
    asm volatile("s_waitcnt lgkmcnt(0)" ::: "memory");
    __builtin_amdgcn_s_barrier();

    float m1 = 1e30f, m2 = 1e30f; int k1 = 0;
    f32x16 aE, dE, aO, dO;

#define VQ_EPI(T, PA, PD)                                                   \
    do {                                                                    \
        const int _kb = (T) * 32 + (hi << 2);                               \
        _Pragma("unroll")                                                   \
        for (int g = 0; g < 4; ++g) {                                       \
            const f32x4 _nr = *reinterpret_cast<const f32x4*>(&s_enorm[_kb + g * 8]); \
            _Pragma("unroll")                                               \
            for (int j = 0; j < 4; ++j) {                                   \
                const int _r = g * 4 + j;                                   \
                float _v = fmaf(-2.0f, PA[_r] + PD[_r], _nr[j]);            \
                int _kk = _kb + g * 8 + j;                                  \
                bool _lt = _v < m1;                                         \
                m2 = fminf(m2, fmaxf(m1, _v));                              \
                k1 = _lt ? _kk : k1;                                        \
                m1 = fminf(m1, _v);                                         \
            }                                                               \
        }                                                                   \
    } while (0)

#define VQ_ITER(T, B, SB, CA, CD, PA, PD, VMN, DOSTAGE, DOEPI)              \
    do {                                                                    \
        vmwait<VMN>();                                                      \
        __builtin_amdgcn_s_barrier();                                       \
        asm volatile("" ::: "memory");                                      \
        CA = ZERO16; CD = ZERO16;                                           \
        __builtin_amdgcn_s_setprio(1);                                      \
        _Pragma("unroll")                                                   \
        for (int s = 0; s < 8; ++s) {                                       \
            const int _u = ((s * 2 + hi) * 32 + lr31) * 8;                  \
            bf16x8 feh = *reinterpret_cast<const bf16x8*>(&ldsE[B][0][_u]); \
            bf16x8 fem = *reinterpret_cast<const bf16x8*>(&ldsE[B][1][_u]); \
            CA = __builtin_amdgcn_mfma_f32_32x32x16_bf16(feh, fxh[s], CA, 0, 0, 0); \
            CD = __builtin_amdgcn_mfma_f32_32x32x16_bf16(feh, fxm[s], CD, 0, 0, 0); \
            CD = __builtin_amdgcn_mfma_f32_32x32x16_bf16(fem, fxh[s], CD, 0, 0, 0); \
        }                                                                   \
        __builtin_amdgcn_s_setprio(0);                                      \
        if (DOSTAGE) { VQ_STAGE((T) + 2, SB); }                             \
        if (DOEPI)   { VQ_EPI((T) - 1, PA, PD); }                           \
    } while (0)

    VQ_ITER(0, 0, 2, aE, dE, aO, dO, 4, 1, 0);
    VQ_ITER(1, 1, 0, aO, dO, aE, dE, 4, 1, 1);
    VQ_ITER(2, 2, 1, aE, dE, aO, dO, 4, 1, 1);
    VQ_ITER(3, 0, 2, aO, dO, aE, dE, 4, 1, 1);
    VQ_ITER(4, 1, 0, aE, dE, aO, dO, 4, 1, 1);
    VQ_ITER(5, 2, 1, aO, dO, aE, dE, 4, 1, 1);
    for (int tb = 6; tb < 30; tb += 6) {
        VQ_ITER(tb + 0, 0, 2, aE, dE, aO, dO, 4, 1, 1);
        VQ_ITER(tb + 1, 1, 0, aO, dO, aE, dE, 4, 1, 1);
        VQ_ITER(tb + 2, 2, 1, aE, dE, aO, dO, 4, 1, 1);
        VQ_ITER(tb + 3, 0, 2, aO, dO, aE, dE, 4, 1, 1);
        VQ_ITER(tb + 4, 1, 0, aE, dE, aO, dO, 4, 1, 1);
        VQ_ITER(tb + 5, 2, 1, aO, dO, aE, dE, 4, 1, 1);
    }
    VQ_ITER(30, 0, 2, aE, dE, aO, dO, 4, 0, 1);
    VQ_ITER(31, 1, 0, aO, dO, aE, dE, 0, 0, 1);
    VQ_EPI(31, aO, dO);
#undef VQ_ITER
#undef VQ_EPI
#undef VQ_STAGE

    // merge the two k-subsets per x-row (lane L and L+32 share row lane&31)
    {
        float om1 = __shfl_xor(m1, 32, 64);
        float om2 = __shfl_xor(m2, 32, 64);
        int   ok1 = __shfl_xor(k1, 32, 64);
        float mx = fmaxf(m1, om1);
        m2 = fminf(fminf(m2, om2), mx);
        bool take = (om1 < m1) || (om1 == m1 && ok1 < k1);
        k1 = take ? ok1 : k1;
        m1 = fminf(m1, om1);
    }

    // loss partial: min distance = m1 + ||x||^2; both duplicated across the
    // lane/lane+32 pair -> 64-lane butterfly sum = 2x row sum -> x0.5.
    {
        float ls = m1 + xn;
        #pragma unroll
        for (int off = 1; off < 64; off <<= 1) ls += __shfl_xor(ls, off, 64);
        if (lane == 0) sloss[wid] = (double)ls * 0.5;
    }
    __syncthreads();
    if (tid == 0)
        partials[blockIdx.x] = (sloss[0] + sloss[1]) + (sloss[2] + sloss[3]);

    if (lane < 32) {
        const int row = rtile + lane;
        if (m2 - m1 < W_DIST) {          // ambiguous under rounding: refine
            int slot = atomicAdd(fb_cnt, 1);
            fb_rows[slot] = row;
        } else {
            bestk[row] = k1;
            idx_out[row] = (float)k1;
        }
    }
}

// ---- exact fallback: block-cooperative, 8 rows per codebook pass ----------
__global__ __launch_bounds__(512) void vq_fallback(
        const float* __restrict__ x, const float* __restrict__ emb,
        const float* __restrict__ enorm,
        const int* __restrict__ fb_cnt, const int* __restrict__ fb_rows,
        int* __restrict__ bestk, float* __restrict__ idx_out) {
    const int tid  = threadIdx.x;
    const int lane = tid & 63;
    const int wid  = tid >> 6;          // 8 waves
    const int nb = *fb_cnt;

    __shared__ float sx[8][DIM];        // 4 KB staged x rows
    __shared__ float s_xn[8];
    __shared__ float swv[8][8];         // [wave][row] candidates
    __shared__ int   swk[8][8];

    const float en0 = enorm[tid];       // k0 = tid
    const float en1 = enorm[tid + 512]; // k1 = tid + 512
    const float4* e0p = reinterpret_cast<const float4*>(emb + (size_t)tid * DIM);
    const float4* e1p = reinterpret_cast<const float4*>(emb + (size_t)(tid + 512) * DIM);

    for (int base = blockIdx.x * 8; base < nb; base += gridDim.x * 8) {
        const int R = min(8, nb - base);
        {
            const int r = tid >> 6;
            const int c2 = (tid & 63) * 2;
            const int slot = fb_rows[min(base + r, nb - 1)];
            float2 v = *reinterpret_cast<const float2*>(x + (size_t)slot * DIM + c2);
            sx[r][c2] = v.x; sx[r][c2 + 1] = v.y;
        }
        __syncthreads();
        if (tid < 8) s_xn[tid] = np_sumsq_128(&sx[tid][0]);
        __syncthreads();

        float a0[8][4], a1[8][4];
        #pragma unroll
        for (int r = 0; r < 8; ++r)
            #pragma unroll
            for (int c = 0; c < 4; ++c) { a0[r][c] = 0.f; a1[r][c] = 0.f; }

        for (int q = 0; q < 32; q += 4) {
            float4 e0v[4], e1v[4];
            #pragma unroll
            for (int j = 0; j < 4; ++j) { e0v[j] = e0p[q + j]; e1v[j] = e1p[q + j]; }
            #pragma unroll
            for (int j = 0; j < 4; ++j) {
                #pragma unroll
                for (int r = 0; r < 8; ++r) {
                    float4 xv = *reinterpret_cast<const float4*>(&sx[r][(q + j) * 4]);
                    a0[r][0] = fmaf(xv.x, e0v[j].x, a0[r][0]);
                    a0[r][1] = fmaf(xv.y, e0v[j].y, a0[r][1]);
                    a0[r][2] = fmaf(xv.z, e0v[j].z, a0[r][2]);
                    a0[r][3] = fmaf(xv.w, e0v[j].w, a0[r][3]);
                    a1[r][0] = fmaf(xv.x, e1v[j].x, a1[r][0]);
                    a1[r][1] = fmaf(xv.y, e1v[j].y, a1[r][1]);
                    a1[r][2] = fmaf(xv.z, e1v[j].z, a1[r][2]);
                    a1[r][3] = fmaf(xv.w, e1v[j].w, a1[r][3]);
                }
            }
        }

        float cv[8]; int ck[8];
        #pragma unroll
        for (int r = 0; r < 8; ++r) {
            float xn = s_xn[r];
            float d0 = __fadd_rn(__fadd_rn(a0[r][0], a0[r][1]),
                                 __fadd_rn(a0[r][2], a0[r][3]));
            float s0 = __fsub_rn(__fadd_rn(xn, en0), __fmul_rn(2.0f, d0));
            float d1 = __fadd_rn(__fadd_rn(a1[r][0], a1[r][1]),
                                 __fadd_rn(a1[r][2], a1[r][3]));
            float s1 = __fsub_rn(__fadd_rn(xn, en1), __fmul_rn(2.0f, d1));
            bool t1 = (s1 < s0);
            cv[r] = t1 ? s1 : s0;
            ck[r] = t1 ? tid + 512 : tid;
        }
        #pragma unroll
        for (int off = 1; off < 64; off <<= 1) {
            #pragma unroll
            for (int r = 0; r < 8; ++r) {
                float ov = __shfl_xor(cv[r], off, 64);
                int   ok = __shfl_xor(ck[r], off, 64);
                bool take = (ov < cv[r]) || (ov == cv[r] && ok < ck[r]);
                cv[r] = take ? ov : cv[r];
                ck[r] = take ? ok : ck[r];
            }
        }
        if (lane == 0) {
            #pragma unroll
            for (int r = 0; r < 8; ++r) { swv[wid][r] = cv[r]; swk[wid][r] = ck[r]; }
        }
        __syncthreads();
        if (tid < R) {
            float bv = swv[0][tid]; int bk = swk[0][tid];
            #pragma unroll
            for (int w = 1; w < 8; ++w) {
                float v = swv[w][tid]; int k = swk[w][tid];
                bool take = (v < bv) || (v == bv && k < bk);
                bv = take ? v : bv;
                bk = take ? k : bk;
            }
            const int row = fb_rows[base + tid];
            bestk[row] = bk;
            idx_out[row] = (float)bk;
        }
        __syncthreads();
    }
}

// ---- gather quantized rows (no x read, no loss math) ----------------------
__global__ __launch_bounds__(256) void vq_gather(
        const float* __restrict__ emb, const int* __restrict__ bestk,
        float* __restrict__ quant) {
    const int t = blockIdx.x * 256 + threadIdx.x;   // 1048576 threads, 8 elems
    const int r = t >> 4;
    const int c = (t & 15) * 8;
    const int bk = bestk[r];
    const float4* ep = reinterpret_cast<const float4*>(emb + (size_t)bk * DIM + c);
    float4 e0 = ep[0], e1 = ep[1];
    float* q = quant + (size_t)r * DIM + c;   // base misaligned by 1 float
    q[0] = e0.x; q[1] = e0.y; q[2] = e0.z; q[3] = e0.w;
    q[4] = e1.x; q[5] = e1.y; q[6] = e1.z; q[7] = e1.w;
}

// ---- final loss: sum 512 block partials in one block ----------------------
__global__ __launch_bounds__(256) void vq_loss(
        const double* __restrict__ partials, float* __restrict__ out) {
    double s = partials[threadIdx.x] + partials[threadIdx.x + 256];
    #pragma unroll
    for (int off = 32; off > 0; off >>= 1) s += __shfl_down(s, off, 64);
    __shared__ double sd[4];
    if ((threadIdx.x & 63) == 0) sd[threadIdx.x >> 6] = s;
    __syncthreads();
    if (threadIdx.x == 0)
        out[0] = (float)(((sd[0] + sd[1]) + (sd[2] + sd[3])) * (1.25 / 8388608.0));
}

extern "C" void kernel_launch(void* const* d_in, const int* in_sizes, int n_in,
                              void* d_out, int out_size, void* d_ws, size_t ws_size,
                              hipStream_t stream) {
    const float* x   = (const float*)d_in[0];   // [32,2048,128] f32
    const float* emb = (const float*)d_in[1];   // [1024,128] f32

    float* out      = (float*)d_out;
    float* loss_out = out;
    float* quant    = out + 1;                        // [8388608]
    float* idx_out  = out + 1 + (size_t)NROWS * DIM;  // [65536] as float

    char* ws = (char*)d_ws;
    int*    fb_cnt   = (int*)(ws + 8);
    float*  enorm    = (float*)(ws + 1024);             // 4 KB
    int*    fb_rows  = (int*)(ws + 16384);              // 256 KB
    int*    bestk    = (int*)(ws + 278528);             // 256 KB
    unsigned short* eh = (unsigned short*)(ws + 557056); // 256 KB
    unsigned short* em = (unsigned short*)(ws + 819200); // 256 KB
    double* partials = (double*)(ws + 1081344);          // 4 KB (512 doubles)

    hipMemsetAsync(ws, 0, 16, stream);
    vq_prep<<<32, 256, 0, stream>>>(emb, enorm, eh, em);
    vq_mfma<<<512, 256, 0, stream>>>(x, eh, em, enorm,
                                     bestk, idx_out, fb_cnt, fb_rows, partials);
    vq_fallback<<<1024, 512, 0, stream>>>(x, emb, enorm, fb_cnt, fb_rows,
                                          bestk, idx_out);
    vq_gather<<<4096, 256, 0, stream>>>(emb, bestk, quant);
    vq_loss<<<1, 256, 0, stream>>>(partials, loss_out);
}